// Round 9
// baseline (268.186 us; speedup 1.0000x reference)
//
#include <hip/hip_runtime.h>

#define DIN 128
#define PB 512            // partition blocks
typedef unsigned short u16;
typedef unsigned int u32;
typedef __attribute__((ext_vector_type(8))) short bf16x8;  // 8 bf16 (4 VGPRs)
typedef __attribute__((ext_vector_type(4))) float f32x4;   // 4 f32 acc

static __device__ __forceinline__ float bf_lo(u32 v) {
    union { u32 u; float f; } c;
    c.u = v << 16;
    return c.f;
}
static __device__ __forceinline__ float bf_hi(u32 v) {
    union { u32 u; float f; } c;
    c.u = v & 0xffff0000u;
    return c.f;
}
static __device__ __forceinline__ u32 f2bf(float f) {
    union { float f; u32 u; } c;
    c.f = f;
    u32 u = c.u;
    u += 0x7fffu + ((u >> 16) & 1u);   // RTNE
    return u >> 16;
}

// ---- wave-64 inclusive scan helper ----
static __device__ __forceinline__ int wave_incl_scan(int x, int lane) {
#pragma unroll
    for (int off = 1; off < 64; off <<= 1) {
        int y = __shfl_up(x, off, 64);
        if (lane >= off) x += y;
    }
    return x;
}

// ---- pass 1: per-block bucket histograms of dst>>8 (-> mat[0:M)) and src>>8 (-> mat[M:2M)) ----
__global__ __launch_bounds__(256) void hist_kernel(
    const int* __restrict__ src, const int* __restrict__ dst,
    u32* __restrict__ mat, int E, int NB, int M) {
    __shared__ u32 hd[512], hs[512];
    int t = threadIdx.x, b = blockIdx.x;
    for (int j = t; j < NB; j += 256) { hd[j] = 0; hs[j] = 0; }
    __syncthreads();
    int chunk = (E + PB - 1) / PB;
    int s = b * chunk, e = min(E, s + chunk);
    for (int i = s + t; i < e; i += 256) {
        atomicAdd(&hd[((u32)dst[i]) >> 8], 1u);
        atomicAdd(&hs[((u32)src[i]) >> 8], 1u);
    }
    __syncthreads();
    for (int j = t; j < NB; j += 256) {
        mat[(size_t)j * PB + b] = hd[j];
        mat[(size_t)M + (size_t)j * PB + b] = hs[j];
    }
}

// ---- per-block exclusive scan; emits block totals ----
__global__ void scan_block_kernel(const int* __restrict__ in, int* __restrict__ out,
                                  int* __restrict__ bsums, int n) {
    __shared__ int wsum[4];
    int i = blockIdx.x * 256 + threadIdx.x;
    int lane = threadIdx.x & 63, wid = threadIdx.x >> 6;
    int v = (i < n) ? in[i] : 0;
    int sc = wave_incl_scan(v, lane);
    if (lane == 63) wsum[wid] = sc;
    __syncthreads();
    int add = 0;
    for (int w = 0; w < wid; ++w) add += wsum[w];
    if (i < n) out[i] = sc - v + add;
    if (threadIdx.x == 255) bsums[blockIdx.x] = sc + add;
}

// ---- single-block exclusive scan of block sums (in-place) ----
__global__ void scan_sums_kernel(int* __restrict__ bsums, int nb) {
    __shared__ int wsum[4];
    __shared__ int carry;
    int lane = threadIdx.x & 63, wid = threadIdx.x >> 6;
    if (threadIdx.x == 0) carry = 0;
    __syncthreads();
    for (int base = 0; base < nb; base += 256) {
        int i = base + threadIdx.x;
        int v = (i < nb) ? bsums[i] : 0;
        int sc = wave_incl_scan(v, lane);
        if (lane == 63) wsum[wid] = sc;
        __syncthreads();
        int add = carry;
        for (int w = 0; w < wid; ++w) add += wsum[w];
        if (i < nb) bsums[i] = sc - v + add;
        __syncthreads();
        if (threadIdx.x == 0) carry += wsum[0] + wsum[1] + wsum[2] + wsum[3];
        __syncthreads();
    }
}

// ---- add scanned block offsets (plain exscan finalize) ----
__global__ void add_off2_kernel(int* __restrict__ out, const int* __restrict__ bsums, int n) {
    int i = blockIdx.x * 256 + threadIdx.x;
    if (i < n) out[i] += bsums[i >> 8];
}

// ---- pass 2: partition edges; part[0:E) dst-tagged, part[E:2E) src (LDS cursors) ----
__global__ __launch_bounds__(256) void part_kernel(
    const int* __restrict__ src, const int* __restrict__ dst,
    const int* __restrict__ off, u32* __restrict__ part, int E, int NB, int M) {
    __shared__ u32 cd[512], cs[512];
    int t = threadIdx.x, b = blockIdx.x;
    for (int j = t; j < NB; j += 256) {
        cd[j] = (u32)off[(size_t)j * PB + b];
        cs[j] = (u32)off[(size_t)M + (size_t)j * PB + b];
    }
    __syncthreads();
    int chunk = (E + PB - 1) / PB;
    int s = b * chunk, e = min(E, s + chunk);
    for (int i = s + t; i < e; i += 256) {
        u32 dv = (u32)dst[i], sv = (u32)src[i];
        u32 p = atomicAdd(&cd[dv >> 8], 1u);
        part[p] = ((dv & 255u) << 24) | sv;
        u32 q = atomicAdd(&cs[sv >> 8], 1u);
        part[q] = sv;
    }
}

// ---- pass 3: per-bucket exact build: rowptr, nd, csr_src, ns ----
__global__ __launch_bounds__(256) void build_kernel(
    const u32* __restrict__ part, const int* __restrict__ off,
    int* __restrict__ rowptr, float* __restrict__ nd, float* __restrict__ ns,
    int* __restrict__ csr_src, int N, int E, int NB, int M) {
    __shared__ u32 lh[256];
    __shared__ u32 cur[256];
    __shared__ int wsum[4];
    int t = threadIdx.x, k = blockIdx.x;
    int lane = t & 63, wid = t >> 6;
    int node = k * 256 + t;

    int beg = off[(size_t)k * PB];
    int end = (k + 1 < NB) ? off[(size_t)(k + 1) * PB] : E;

    lh[t] = 0;
    __syncthreads();
    for (int i = beg + t; i < end; i += 256)
        atomicAdd(&lh[part[i] >> 24], 1u);
    __syncthreads();

    int cnt = (int)lh[t];
    int sc = wave_incl_scan(cnt, lane);
    if (lane == 63) wsum[wid] = sc;
    __syncthreads();
    int add = 0;
    for (int w = 0; w < wid; ++w) add += wsum[w];
    int ex = sc - cnt + add;

    if (node < N) {
        rowptr[node] = beg + ex;
        nd[node] = rsqrtf(fmaxf((float)cnt, 1.0f));
    }
    if (k == 0 && t == 0) rowptr[N] = E;
    cur[t] = (u32)(beg + ex);
    __syncthreads();

    for (int i = beg + t; i < end; i += 256) {
        u32 v = part[i];
        u32 pos = atomicAdd(&cur[v >> 24], 1u);
        csr_src[pos] = (int)(v & 0xFFFFFFu);
    }

    // src side: exact outdeg histogram -> ns (absolute offsets into part[E:2E))
    int beg2 = off[(size_t)M + (size_t)k * PB];
    int end2 = (k + 1 < NB) ? off[(size_t)M + (size_t)(k + 1) * PB] : 2 * E;
    __syncthreads();
    lh[t] = 0;
    __syncthreads();
    for (int i = beg2 + t; i < end2; i += 256)
        atomicAdd(&lh[part[i] & 255u], 1u);
    __syncthreads();
    if (node < N) ns[node] = rsqrtf(fmaxf((float)lh[t], 1.0f));
}

// ---- gather (layer 1), XCD-sliced: slice = bid&7 (16 cols, 32B), 8 lanes/node ----
// t1/h2 stored slice-major: [8][N][8] u32 (16 bf16 per node-slice).
// h2 = relu(nd * sum t1[src] + b1)
__global__ __launch_bounds__(256, 8) void gather128s_kernel(
    const u32* __restrict__ tsl, const int* __restrict__ rowptr,
    const int* __restrict__ csr_src, const float* __restrict__ nd,
    const float* __restrict__ bias, u32* __restrict__ h2sl, int N) {
    int bid = blockIdx.x;
    int slice = bid & 7;
    int nb = bid >> 3;
    int tid = threadIdx.x;
    int g = tid >> 3;                  // 32 node-groups per block
    int w = tid & 7;                   // u32 word in slice (2 cols)
    int node = nb * 32 + g;
    bool valid = node < N;
    int nc = valid ? node : 0;
    int beg = rowptr[nc];
    int cnt = valid ? (rowptr[nc + 1] - beg) : 0;
    const int* ip = csr_src + beg;
    const u32* ts = tsl + (size_t)slice * N * 8;

    float a0 = 0.f, a1 = 0.f;
    int j = 0;
    for (; j + 4 <= cnt; j += 4) {
        int s0 = ip[j], s1 = ip[j + 1], s2 = ip[j + 2], s3 = ip[j + 3];
        u32 v0 = ts[s0 * 8 + w];
        u32 v1 = ts[s1 * 8 + w];
        u32 v2 = ts[s2 * 8 + w];
        u32 v3 = ts[s3 * 8 + w];
        a0 += bf_lo(v0) + bf_lo(v1) + bf_lo(v2) + bf_lo(v3);
        a1 += bf_hi(v0) + bf_hi(v1) + bf_hi(v2) + bf_hi(v3);
    }
    for (; j < cnt; ++j) {
        u32 v = ts[ip[j] * 8 + w];
        a0 += bf_lo(v); a1 += bf_hi(v);
    }

    if (valid) {
        float sc = nd[nc];
        float2 bv = reinterpret_cast<const float2*>(bias)[slice * 8 + w];
        float r0 = fmaxf(fmaf(a0, sc, bv.x), 0.f);
        float r1 = fmaxf(fmaf(a1, sc, bv.y), 0.f);
        h2sl[(size_t)slice * N * 8 + (size_t)node * 8 + w] = f2bf(r0) | (f2bf(r1) << 16);
    }
}

// ---- gather (layer 2), XCD-sliced: slice = bid&7 (8 cols, 16B), 4 lanes/node ----
// t2 slice-major [8][N][4] u32; out f32 row-major [N][64].
__global__ __launch_bounds__(256, 8) void gather64s_kernel(
    const u32* __restrict__ tsl, const int* __restrict__ rowptr,
    const int* __restrict__ csr_src, const float* __restrict__ nd,
    const float* __restrict__ bias, float* __restrict__ out, int N) {
    int bid = blockIdx.x;
    int slice = bid & 7;
    int nb = bid >> 3;
    int tid = threadIdx.x;
    int g = tid >> 2;                  // 64 node-groups per block
    int w = tid & 3;                   // u32 word in slice (2 cols)
    int node = nb * 64 + g;
    bool valid = node < N;
    int nc = valid ? node : 0;
    int beg = rowptr[nc];
    int cnt = valid ? (rowptr[nc + 1] - beg) : 0;
    const int* ip = csr_src + beg;
    const u32* ts = tsl + (size_t)slice * N * 4;

    float a0 = 0.f, a1 = 0.f;
    int j = 0;
    for (; j + 4 <= cnt; j += 4) {
        int s0 = ip[j], s1 = ip[j + 1], s2 = ip[j + 2], s3 = ip[j + 3];
        u32 v0 = ts[s0 * 4 + w];
        u32 v1 = ts[s1 * 4 + w];
        u32 v2 = ts[s2 * 4 + w];
        u32 v3 = ts[s3 * 4 + w];
        a0 += bf_lo(v0) + bf_lo(v1) + bf_lo(v2) + bf_lo(v3);
        a1 += bf_hi(v0) + bf_hi(v1) + bf_hi(v2) + bf_hi(v3);
    }
    for (; j < cnt; ++j) {
        u32 v = ts[ip[j] * 4 + w];
        a0 += bf_lo(v); a1 += bf_hi(v);
    }

    if (valid) {
        float sc = nd[nc];
        float2 bv = reinterpret_cast<const float2*>(bias)[slice * 4 + w];
        float2 o;
        o.x = fmaf(a0, sc, bv.x);
        o.y = fmaf(a1, sc, bv.y);
        *reinterpret_cast<float2*>(out + (size_t)node * 64 + slice * 8 + 2 * w) = o;
    }
}

// ---- MFMA GEMM with slice-major I/O ----
// LAYER2=false: A = f32 row-major [n][128], out = t1 slice-major [8][n][16]bf16, DOUT=128
// LAYER2=true:  A = bf16 slice-major [8][n][16] (h2), out = t2 slice-major [8][n][8]bf16, DOUT=64
template <bool LAYER2>
__global__ __launch_bounds__(256) void gemm_mfma_kernel(
    const void* __restrict__ Av, const float* __restrict__ W,
    const float* __restrict__ scale, u16* __restrict__ out, int n) {
    constexpr int DOUT = LAYER2 ? 64 : 128;
    constexpr int NT = DOUT / 16;       // col tiles
    constexpr int WK = DIN + 8;         // padded k-stride in bf16 units
    __shared__ u16 Wt[DOUT * WK];

    for (int i = threadIdx.x; i < DIN * DOUT; i += 256) {
        int k = i / DOUT, c = i % DOUT;
        Wt[c * WK + k] = (u16)f2bf(W[i]);
    }

    int lane = threadIdx.x & 63;
    int wid = threadIdx.x >> 6;
    int row = blockIdx.x * 64 + wid * 16 + (lane & 15);
    int rc = min(row, n - 1);
    int kg = lane >> 4;                 // k-group 0..3

    bf16x8 afrag[4];
    if (LAYER2) {
        const u16* ap = (const u16*)Av;
#pragma unroll
        for (int s = 0; s < 4; ++s) {
            // k = s*32 + kg*8 .. +7 lives in slice 2s+(kg>>1), offset (kg&1)*8
            const u16* p = ap + (size_t)(2 * s + (kg >> 1)) * n * 16 + (size_t)rc * 16 + (kg & 1) * 8;
            uint4 v = *reinterpret_cast<const uint4*>(p);
            afrag[s] = *reinterpret_cast<bf16x8*>(&v);
        }
    } else {
        const float* ap = (const float*)Av + (size_t)rc * DIN + kg * 8;
#pragma unroll
        for (int s = 0; s < 4; ++s) {
            float4 v0 = *reinterpret_cast<const float4*>(ap + s * 32);
            float4 v1 = *reinterpret_cast<const float4*>(ap + s * 32 + 4);
            uint4 v;
            v.x = f2bf(v0.x) | (f2bf(v0.y) << 16);
            v.y = f2bf(v0.z) | (f2bf(v0.w) << 16);
            v.z = f2bf(v1.x) | (f2bf(v1.y) << 16);
            v.w = f2bf(v1.z) | (f2bf(v1.w) << 16);
            afrag[s] = *reinterpret_cast<bf16x8*>(&v);
        }
    }

    f32x4 acc[NT];
#pragma unroll
    for (int t = 0; t < NT; ++t) acc[t] = (f32x4){0.f, 0.f, 0.f, 0.f};

    __syncthreads();                    // Wt ready

#pragma unroll
    for (int t = 0; t < NT; ++t) {
        const u16* wp = Wt + (t * 16 + (lane & 15)) * WK + kg * 8;
#pragma unroll
        for (int s = 0; s < 4; ++s) {
            uint4 wv = *reinterpret_cast<const uint4*>(wp + s * 32);
            bf16x8 wfrag = *reinterpret_cast<bf16x8*>(&wv);
            acc[t] = __builtin_amdgcn_mfma_f32_16x16x32_bf16(wfrag, afrag[s], acc[t], 0, 0, 0);
        }
    }

    if (row < n) {
        float sc = scale[row];
        uint2* ob = reinterpret_cast<uint2*>(out);
#pragma unroll
        for (int t = 0; t < NT; ++t) {
            uint2 v;
            v.x = f2bf(acc[t][0] * sc) | (f2bf(acc[t][1] * sc) << 16);
            v.y = f2bf(acc[t][2] * sc) | (f2bf(acc[t][3] * sc) << 16);
            if (LAYER2) {
                // cols t*16+kg*4.. -> slice 2t+(kg>>1), uint2 offset (kg&1)
                ob[(size_t)(2 * t + (kg >> 1)) * n * 2 + (size_t)row * 2 + (kg & 1)] = v;
            } else {
                // cols t*16+kg*4.. -> slice t, uint2 offset kg
                ob[(size_t)t * n * 4 + (size_t)row * 4 + kg] = v;
            }
        }
    }
}

extern "C" void kernel_launch(void* const* d_in, const int* in_sizes, int n_in,
                              void* d_out, int out_size, void* d_ws, size_t ws_size,
                              hipStream_t stream) {
    const float* feature = (const float*)d_in[0];
    const int*   src     = (const int*)d_in[1];
    const int*   dst     = (const int*)d_in[2];
    const float* W1      = (const float*)d_in[3];
    const float* b1      = (const float*)d_in[4];
    const float* W2      = (const float*)d_in[5];
    const float* b2      = (const float*)d_in[6];

    const int N = in_sizes[0] / DIN;
    const int E = in_sizes[1];
    const int NB = (N + 255) >> 8;            // buckets (<=512 for N<=131072)
    const int M = NB * PB;                    // per-side count-matrix size
    const int M2 = 2 * M;                     // concatenated (dst|src)
    const int nbm = (M2 + 255) / 256;

    char* ws = (char*)d_ws;
    size_t off_b = 0;
    auto take = [&](size_t bytes) -> void* {
        void* p = ws + off_b;
        off_b += (bytes + 255) & ~(size_t)255;
        return p;
    };
    float* ns      = (float*)take((size_t)N * 4);
    float* nd      = (float*)take((size_t)N * 4);
    int*   rowptr  = (int*)take((size_t)(N + 1) * 4);
    int*   csr_src = (int*)take((size_t)E * 4);
    u32*   mat     = (u32*)take((size_t)M2 * 4);
    int*   off     = (int*)take((size_t)M2 * 4);
    int*   bs      = (int*)take((size_t)(nbm + 4) * 4);
    u32*   part    = (u32*)take((size_t)2 * E * 4);
    u16*   t1      = (u16*)take((size_t)N * DIN * 2);  // slice-major; reused as t2
    u16*   h2      = (u16*)take((size_t)N * DIN * 2);  // slice-major

    // CSR build: hist -> single concatenated scan -> partition -> per-bucket build
    hist_kernel<<<PB, 256, 0, stream>>>(src, dst, mat, E, NB, M);
    scan_block_kernel<<<nbm, 256, 0, stream>>>((const int*)mat, off, bs, M2);
    scan_sums_kernel<<<1, 256, 0, stream>>>(bs, nbm);
    add_off2_kernel<<<nbm, 256, 0, stream>>>(off, bs, M2);
    part_kernel<<<PB, 256, 0, stream>>>(src, dst, off, part, E, NB, M);
    build_kernel<<<NB, 256, 0, stream>>>(part, off, rowptr, nd, ns, csr_src, N, E, NB, M);

    // Layer 1: t1 = bf16((X @ W1) * ns) sliced; h2 = bf16(relu(gather(t1) * nd + b1)) sliced
    gemm_mfma_kernel<false><<<(N + 63) / 64, 256, 0, stream>>>(feature, W1, ns, t1, N);
    gather128s_kernel<<<8 * ((N + 31) / 32), 256, 0, stream>>>(
        (const u32*)t1, rowptr, csr_src, nd, b1, (u32*)h2, N);

    // Layer 2: t2 = bf16((h2 @ W2) * ns) sliced; out = gather(t2) * nd + b2 (f32 row-major)
    gemm_mfma_kernel<true><<<(N + 63) / 64, 256, 0, stream>>>(h2, W2, ns, t1, N);
    gather64s_kernel<<<8 * ((N + 63) / 64), 256, 0, stream>>>(
        (const u32*)t1, rowptr, csr_src, nd, b2, (float*)d_out, N);
}

// Round 10
// 222.881 us; speedup vs baseline: 1.2033x; 1.2033x over previous
//
#include <hip/hip_runtime.h>

#define DIN 128
#define PB 512            // partition blocks
typedef unsigned short u16;
typedef unsigned int u32;
typedef __attribute__((ext_vector_type(8))) short bf16x8;  // 8 bf16 (4 VGPRs)
typedef __attribute__((ext_vector_type(4))) float f32x4;   // 4 f32 acc

static __device__ __forceinline__ float bf_lo(u32 v) {
    union { u32 u; float f; } c;
    c.u = v << 16;
    return c.f;
}
static __device__ __forceinline__ float bf_hi(u32 v) {
    union { u32 u; float f; } c;
    c.u = v & 0xffff0000u;
    return c.f;
}
static __device__ __forceinline__ u32 f2bf(float f) {
    union { float f; u32 u; } c;
    c.f = f;
    u32 u = c.u;
    u += 0x7fffu + ((u >> 16) & 1u);   // RTNE
    return u >> 16;
}

// ---- wave-64 inclusive scan helper ----
static __device__ __forceinline__ int wave_incl_scan(int x, int lane) {
#pragma unroll
    for (int off = 1; off < 64; off <<= 1) {
        int y = __shfl_up(x, off, 64);
        if (lane >= off) x += y;
    }
    return x;
}

// ---- pass 1: per-block bucket histograms of dst>>8 (-> mat[0:M)) and src>>8 (-> mat[M:2M)) ----
__global__ __launch_bounds__(256) void hist_kernel(
    const int* __restrict__ src, const int* __restrict__ dst,
    u32* __restrict__ mat, int E, int NB, int M) {
    __shared__ u32 hd[512], hs[512];
    int t = threadIdx.x, b = blockIdx.x;
    for (int j = t; j < NB; j += 256) { hd[j] = 0; hs[j] = 0; }
    __syncthreads();
    int chunk = (E + PB - 1) / PB;
    int s = b * chunk, e = min(E, s + chunk);
    for (int i = s + t; i < e; i += 256) {
        atomicAdd(&hd[((u32)dst[i]) >> 8], 1u);
        atomicAdd(&hs[((u32)src[i]) >> 8], 1u);
    }
    __syncthreads();
    for (int j = t; j < NB; j += 256) {
        mat[(size_t)j * PB + b] = hd[j];
        mat[(size_t)M + (size_t)j * PB + b] = hs[j];
    }
}

// ---- per-block exclusive scan; emits block totals ----
__global__ void scan_block_kernel(const int* __restrict__ in, int* __restrict__ out,
                                  int* __restrict__ bsums, int n) {
    __shared__ int wsum[4];
    int i = blockIdx.x * 256 + threadIdx.x;
    int lane = threadIdx.x & 63, wid = threadIdx.x >> 6;
    int v = (i < n) ? in[i] : 0;
    int sc = wave_incl_scan(v, lane);
    if (lane == 63) wsum[wid] = sc;
    __syncthreads();
    int add = 0;
    for (int w = 0; w < wid; ++w) add += wsum[w];
    if (i < n) out[i] = sc - v + add;
    if (threadIdx.x == 255) bsums[blockIdx.x] = sc + add;
}

// ---- single-block exclusive scan of block sums (in-place) ----
__global__ void scan_sums_kernel(int* __restrict__ bsums, int nb) {
    __shared__ int wsum[4];
    __shared__ int carry;
    int lane = threadIdx.x & 63, wid = threadIdx.x >> 6;
    if (threadIdx.x == 0) carry = 0;
    __syncthreads();
    for (int base = 0; base < nb; base += 256) {
        int i = base + threadIdx.x;
        int v = (i < nb) ? bsums[i] : 0;
        int sc = wave_incl_scan(v, lane);
        if (lane == 63) wsum[wid] = sc;
        __syncthreads();
        int add = carry;
        for (int w = 0; w < wid; ++w) add += wsum[w];
        if (i < nb) bsums[i] = sc - v + add;
        __syncthreads();
        if (threadIdx.x == 0) carry += wsum[0] + wsum[1] + wsum[2] + wsum[3];
        __syncthreads();
    }
}

// ---- add scanned block offsets (plain exscan finalize) ----
__global__ void add_off2_kernel(int* __restrict__ out, const int* __restrict__ bsums, int n) {
    int i = blockIdx.x * 256 + threadIdx.x;
    if (i < n) out[i] += bsums[i >> 8];
}

// ---- pass 2: partition edges; part[0:E) dst-tagged, part[E:2E) src (LDS cursors) ----
__global__ __launch_bounds__(256) void part_kernel(
    const int* __restrict__ src, const int* __restrict__ dst,
    const int* __restrict__ off, u32* __restrict__ part, int E, int NB, int M) {
    __shared__ u32 cd[512], cs[512];
    int t = threadIdx.x, b = blockIdx.x;
    for (int j = t; j < NB; j += 256) {
        cd[j] = (u32)off[(size_t)j * PB + b];
        cs[j] = (u32)off[(size_t)M + (size_t)j * PB + b];
    }
    __syncthreads();
    int chunk = (E + PB - 1) / PB;
    int s = b * chunk, e = min(E, s + chunk);
    for (int i = s + t; i < e; i += 256) {
        u32 dv = (u32)dst[i], sv = (u32)src[i];
        u32 p = atomicAdd(&cd[dv >> 8], 1u);
        part[p] = ((dv & 255u) << 24) | sv;
        u32 q = atomicAdd(&cs[sv >> 8], 1u);
        part[q] = sv;
    }
}

// ---- pass 3: per-bucket exact build: rowptr, nd, csr_src, ns ----
__global__ __launch_bounds__(256) void build_kernel(
    const u32* __restrict__ part, const int* __restrict__ off,
    int* __restrict__ rowptr, float* __restrict__ nd, float* __restrict__ ns,
    int* __restrict__ csr_src, int N, int E, int NB, int M) {
    __shared__ u32 lh[256];
    __shared__ u32 cur[256];
    __shared__ int wsum[4];
    int t = threadIdx.x, k = blockIdx.x;
    int lane = t & 63, wid = t >> 6;
    int node = k * 256 + t;

    int beg = off[(size_t)k * PB];
    int end = (k + 1 < NB) ? off[(size_t)(k + 1) * PB] : E;

    lh[t] = 0;
    __syncthreads();
    for (int i = beg + t; i < end; i += 256)
        atomicAdd(&lh[part[i] >> 24], 1u);
    __syncthreads();

    int cnt = (int)lh[t];
    int sc = wave_incl_scan(cnt, lane);
    if (lane == 63) wsum[wid] = sc;
    __syncthreads();
    int add = 0;
    for (int w = 0; w < wid; ++w) add += wsum[w];
    int ex = sc - cnt + add;

    if (node < N) {
        rowptr[node] = beg + ex;
        nd[node] = rsqrtf(fmaxf((float)cnt, 1.0f));
    }
    if (k == 0 && t == 0) rowptr[N] = E;
    cur[t] = (u32)(beg + ex);
    __syncthreads();

    for (int i = beg + t; i < end; i += 256) {
        u32 v = part[i];
        u32 pos = atomicAdd(&cur[v >> 24], 1u);
        csr_src[pos] = (int)(v & 0xFFFFFFu);
    }

    // src side: exact outdeg histogram -> ns (absolute offsets into part[E:2E))
    int beg2 = off[(size_t)M + (size_t)k * PB];
    int end2 = (k + 1 < NB) ? off[(size_t)M + (size_t)(k + 1) * PB] : 2 * E;
    __syncthreads();
    lh[t] = 0;
    __syncthreads();
    for (int i = beg2 + t; i < end2; i += 256)
        atomicAdd(&lh[part[i] & 255u], 1u);
    __syncthreads();
    if (node < N) ns[node] = rsqrtf(fmaxf((float)lh[t], 1.0f));
}

// ---- gather (layer 1), XCD-sliced, 8-deep MLP: slice = bid&7 (16 cols), 8 lanes/node ----
// t1/h2 slice-major [8][N][8] u32. h2 = relu(nd * sum t1[src] + b1)
__global__ __launch_bounds__(256, 8) void gather128s_kernel(
    const u32* __restrict__ tsl, const int* __restrict__ rowptr,
    const int* __restrict__ csr_src, const float* __restrict__ nd,
    const float* __restrict__ bias, u32* __restrict__ h2sl, int N) {
    int bid = blockIdx.x;
    int slice = bid & 7;
    int nb = bid >> 3;
    int tid = threadIdx.x;
    int g = tid >> 3;                  // 32 node-groups per block
    int w = tid & 7;                   // u32 word in slice (2 cols)
    int node = nb * 32 + g;
    bool valid = node < N;
    int nc = valid ? node : 0;
    int beg = rowptr[nc];
    int cnt = valid ? (rowptr[nc + 1] - beg) : 0;
    const int* ip = csr_src + beg;
    const u32* ts = tsl + (size_t)slice * N * 8 + w;

    float a0 = 0.f, a1 = 0.f;
    int j = 0;
    for (; j + 8 <= cnt; j += 8) {
        int s[8]; u32 v[8];
#pragma unroll
        for (int k = 0; k < 8; ++k) s[k] = ip[j + k];
#pragma unroll
        for (int k = 0; k < 8; ++k) v[k] = ts[(size_t)s[k] * 8];
#pragma unroll
        for (int k = 0; k < 8; ++k) { a0 += bf_lo(v[k]); a1 += bf_hi(v[k]); }
    }
    if (j + 4 <= cnt) {
        int s[4]; u32 v[4];
#pragma unroll
        for (int k = 0; k < 4; ++k) s[k] = ip[j + k];
#pragma unroll
        for (int k = 0; k < 4; ++k) v[k] = ts[(size_t)s[k] * 8];
#pragma unroll
        for (int k = 0; k < 4; ++k) { a0 += bf_lo(v[k]); a1 += bf_hi(v[k]); }
        j += 4;
    }
    if (j + 2 <= cnt) {
        u32 v0 = ts[(size_t)ip[j] * 8];
        u32 v1 = ts[(size_t)ip[j + 1] * 8];
        a0 += bf_lo(v0) + bf_lo(v1);
        a1 += bf_hi(v0) + bf_hi(v1);
        j += 2;
    }
    if (j < cnt) {
        u32 v0 = ts[(size_t)ip[j] * 8];
        a0 += bf_lo(v0); a1 += bf_hi(v0);
    }

    if (valid) {
        float sc = nd[nc];
        float2 bv = reinterpret_cast<const float2*>(bias)[slice * 8 + w];
        float r0 = fmaxf(fmaf(a0, sc, bv.x), 0.f);
        float r1 = fmaxf(fmaf(a1, sc, bv.y), 0.f);
        h2sl[(size_t)slice * N * 8 + (size_t)node * 8 + w] = f2bf(r0) | (f2bf(r1) << 16);
    }
}

// ---- gather (layer 2), unsliced, 8-deep MLP: 16 lanes/node, uint2 per lane ----
// t2 row-major [N][64] bf16 (= [N][16] uint2); out f32 row-major [N][64].
__global__ __launch_bounds__(256, 8) void gather64_kernel(
    const uint2* __restrict__ tp, const int* __restrict__ rowptr,
    const int* __restrict__ csr_src, const float* __restrict__ nd,
    const float* __restrict__ bias, float* __restrict__ out, int N) {
    int tid = threadIdx.x;
    int g = tid >> 4;                  // 16 node-groups per block
    int w = tid & 15;                  // uint2 word: cols 4w..4w+3
    int node = blockIdx.x * 16 + g;
    bool valid = node < N;
    int nc = valid ? node : 0;
    int beg = rowptr[nc];
    int cnt = valid ? (rowptr[nc + 1] - beg) : 0;
    const int* ip = csr_src + beg;
    const uint2* ts = tp + w;

    float a0 = 0.f, a1 = 0.f, a2 = 0.f, a3 = 0.f;
    int j = 0;
    for (; j + 8 <= cnt; j += 8) {
        int s[8]; uint2 v[8];
#pragma unroll
        for (int k = 0; k < 8; ++k) s[k] = ip[j + k];
#pragma unroll
        for (int k = 0; k < 8; ++k) v[k] = ts[(size_t)s[k] * 16];
#pragma unroll
        for (int k = 0; k < 8; ++k) {
            a0 += bf_lo(v[k].x); a1 += bf_hi(v[k].x);
            a2 += bf_lo(v[k].y); a3 += bf_hi(v[k].y);
        }
    }
    if (j + 4 <= cnt) {
        int s[4]; uint2 v[4];
#pragma unroll
        for (int k = 0; k < 4; ++k) s[k] = ip[j + k];
#pragma unroll
        for (int k = 0; k < 4; ++k) v[k] = ts[(size_t)s[k] * 16];
#pragma unroll
        for (int k = 0; k < 4; ++k) {
            a0 += bf_lo(v[k].x); a1 += bf_hi(v[k].x);
            a2 += bf_lo(v[k].y); a3 += bf_hi(v[k].y);
        }
        j += 4;
    }
    if (j + 2 <= cnt) {
        uint2 v0 = ts[(size_t)ip[j] * 16];
        uint2 v1 = ts[(size_t)ip[j + 1] * 16];
        a0 += bf_lo(v0.x) + bf_lo(v1.x); a1 += bf_hi(v0.x) + bf_hi(v1.x);
        a2 += bf_lo(v0.y) + bf_lo(v1.y); a3 += bf_hi(v0.y) + bf_hi(v1.y);
        j += 2;
    }
    if (j < cnt) {
        uint2 v0 = ts[(size_t)ip[j] * 16];
        a0 += bf_lo(v0.x); a1 += bf_hi(v0.x);
        a2 += bf_lo(v0.y); a3 += bf_hi(v0.y);
    }

    if (valid) {
        float sc = nd[nc];
        float4 bv = reinterpret_cast<const float4*>(bias)[w];
        float4 o;
        o.x = fmaf(a0, sc, bv.x);
        o.y = fmaf(a1, sc, bv.y);
        o.z = fmaf(a2, sc, bv.z);
        o.w = fmaf(a3, sc, bv.w);
        *reinterpret_cast<float4*>(out + (size_t)node * 64 + 4 * w) = o;
    }
}

// ---- MFMA GEMM ----
// LAYER2=false: A = f32 row-major [n][128], out = t1 slice-major [8][n][16]bf16, DOUT=128
// LAYER2=true:  A = bf16 slice-major [8][n][16] (h2), out = t2 ROW-major [n][64]bf16, DOUT=64
template <bool LAYER2>
__global__ __launch_bounds__(256) void gemm_mfma_kernel(
    const void* __restrict__ Av, const float* __restrict__ W,
    const float* __restrict__ scale, u16* __restrict__ out, int n) {
    constexpr int DOUT = LAYER2 ? 64 : 128;
    constexpr int NT = DOUT / 16;       // col tiles
    constexpr int WK = DIN + 8;         // padded k-stride in bf16 units
    __shared__ u16 Wt[DOUT * WK];

    for (int i = threadIdx.x; i < DIN * DOUT; i += 256) {
        int k = i / DOUT, c = i % DOUT;
        Wt[c * WK + k] = (u16)f2bf(W[i]);
    }

    int lane = threadIdx.x & 63;
    int wid = threadIdx.x >> 6;
    int row = blockIdx.x * 64 + wid * 16 + (lane & 15);
    int rc = min(row, n - 1);
    int kg = lane >> 4;                 // k-group 0..3

    bf16x8 afrag[4];
    if (LAYER2) {
        const u16* ap = (const u16*)Av;
#pragma unroll
        for (int s = 0; s < 4; ++s) {
            // k = s*32 + kg*8 .. +7 lives in slice 2s+(kg>>1), offset (kg&1)*8
            const u16* p = ap + (size_t)(2 * s + (kg >> 1)) * n * 16 + (size_t)rc * 16 + (kg & 1) * 8;
            uint4 v = *reinterpret_cast<const uint4*>(p);
            afrag[s] = *reinterpret_cast<bf16x8*>(&v);
        }
    } else {
        const float* ap = (const float*)Av + (size_t)rc * DIN + kg * 8;
#pragma unroll
        for (int s = 0; s < 4; ++s) {
            float4 v0 = *reinterpret_cast<const float4*>(ap + s * 32);
            float4 v1 = *reinterpret_cast<const float4*>(ap + s * 32 + 4);
            uint4 v;
            v.x = f2bf(v0.x) | (f2bf(v0.y) << 16);
            v.y = f2bf(v0.z) | (f2bf(v0.w) << 16);
            v.z = f2bf(v1.x) | (f2bf(v1.y) << 16);
            v.w = f2bf(v1.z) | (f2bf(v1.w) << 16);
            afrag[s] = *reinterpret_cast<bf16x8*>(&v);
        }
    }

    f32x4 acc[NT];
#pragma unroll
    for (int t = 0; t < NT; ++t) acc[t] = (f32x4){0.f, 0.f, 0.f, 0.f};

    __syncthreads();                    // Wt ready

#pragma unroll
    for (int t = 0; t < NT; ++t) {
        const u16* wp = Wt + (t * 16 + (lane & 15)) * WK + kg * 8;
#pragma unroll
        for (int s = 0; s < 4; ++s) {
            uint4 wv = *reinterpret_cast<const uint4*>(wp + s * 32);
            bf16x8 wfrag = *reinterpret_cast<bf16x8*>(&wv);
            acc[t] = __builtin_amdgcn_mfma_f32_16x16x32_bf16(wfrag, afrag[s], acc[t], 0, 0, 0);
        }
    }

    if (row < n) {
        float sc = scale[row];
#pragma unroll
        for (int t = 0; t < NT; ++t) {
            uint2 v;
            v.x = f2bf(acc[t][0] * sc) | (f2bf(acc[t][1] * sc) << 16);
            v.y = f2bf(acc[t][2] * sc) | (f2bf(acc[t][3] * sc) << 16);
            if (LAYER2) {
                // row-major: cols t*16 + kg*4 .. +3
                *reinterpret_cast<uint2*>(out + (size_t)row * 64 + t * 16 + kg * 4) = v;
            } else {
                // slice-major: cols t*16+kg*4.. -> slice t, uint2 offset kg
                reinterpret_cast<uint2*>(out)[(size_t)t * n * 4 + (size_t)row * 4 + kg] = v;
            }
        }
    }
}

extern "C" void kernel_launch(void* const* d_in, const int* in_sizes, int n_in,
                              void* d_out, int out_size, void* d_ws, size_t ws_size,
                              hipStream_t stream) {
    const float* feature = (const float*)d_in[0];
    const int*   src     = (const int*)d_in[1];
    const int*   dst     = (const int*)d_in[2];
    const float* W1      = (const float*)d_in[3];
    const float* b1      = (const float*)d_in[4];
    const float* W2      = (const float*)d_in[5];
    const float* b2      = (const float*)d_in[6];

    const int N = in_sizes[0] / DIN;
    const int E = in_sizes[1];
    const int NB = (N + 255) >> 8;            // buckets (<=512 for N<=131072)
    const int M = NB * PB;                    // per-side count-matrix size
    const int M2 = 2 * M;                     // concatenated (dst|src)
    const int nbm = (M2 + 255) / 256;

    char* ws = (char*)d_ws;
    size_t off_b = 0;
    auto take = [&](size_t bytes) -> void* {
        void* p = ws + off_b;
        off_b += (bytes + 255) & ~(size_t)255;
        return p;
    };
    float* ns      = (float*)take((size_t)N * 4);
    float* nd      = (float*)take((size_t)N * 4);
    int*   rowptr  = (int*)take((size_t)(N + 1) * 4);
    int*   csr_src = (int*)take((size_t)E * 4);
    u32*   mat     = (u32*)take((size_t)M2 * 4);
    int*   off     = (int*)take((size_t)M2 * 4);
    int*   bs      = (int*)take((size_t)(nbm + 4) * 4);
    u32*   part    = (u32*)take((size_t)2 * E * 4);
    u16*   t1      = (u16*)take((size_t)N * DIN * 2);  // L1: slice-major; L2: t2 row-major
    u16*   h2      = (u16*)take((size_t)N * DIN * 2);  // slice-major

    // CSR build: hist -> single concatenated scan -> partition -> per-bucket build
    hist_kernel<<<PB, 256, 0, stream>>>(src, dst, mat, E, NB, M);
    scan_block_kernel<<<nbm, 256, 0, stream>>>((const int*)mat, off, bs, M2);
    scan_sums_kernel<<<1, 256, 0, stream>>>(bs, nbm);
    add_off2_kernel<<<nbm, 256, 0, stream>>>(off, bs, M2);
    part_kernel<<<PB, 256, 0, stream>>>(src, dst, off, part, E, NB, M);
    build_kernel<<<NB, 256, 0, stream>>>(part, off, rowptr, nd, ns, csr_src, N, E, NB, M);

    // Layer 1: t1 = bf16((X @ W1) * ns) sliced; h2 = bf16(relu(gather(t1) * nd + b1)) sliced
    gemm_mfma_kernel<false><<<(N + 63) / 64, 256, 0, stream>>>(feature, W1, ns, t1, N);
    gather128s_kernel<<<8 * ((N + 31) / 32), 256, 0, stream>>>(
        (const u32*)t1, rowptr, csr_src, nd, b1, (u32*)h2, N);

    // Layer 2: t2 = bf16((h2 @ W2) * ns) row-major; out = gather(t2) * nd + b2 (f32)
    gemm_mfma_kernel<true><<<(N + 63) / 64, 256, 0, stream>>>(h2, W2, ns, t1, N);
    gather64_kernel<<<(N + 15) / 16, 256, 0, stream>>>(
        (const uint2*)t1, rowptr, csr_src, nd, b2, (float*)d_out, N);
}